// Round 10
// baseline (434.907 us; speedup 1.0000x reference)
//
#include <hip/hip_runtime.h>
#include <math.h>

#define N_NODES 50000
#define N_EDGES 1000000
#define HID 64
#define SCAN_NB ((N_NODES + 1 + 255) / 256)
#define NBP 512   // pool blocks (2 per CU)
static_assert(N_NODES <= 65536, "src must fit in 16 bits");

typedef __attribute__((ext_vector_type(8))) short short8;   // 8 bf16 = 4 VGPRs
typedef __attribute__((ext_vector_type(4))) float f32x4;

__device__ __forceinline__ unsigned short f2bf(float x) {   // RNE float->bf16
    unsigned u = __float_as_uint(x);
    u += 0x7FFFu + ((u >> 16) & 1u);
    return (unsigned short)(u >> 16);
}
__device__ __forceinline__ float bfbits_hi(unsigned pk) {   // high-16 bf16 -> f32
    return __uint_as_float(pk & 0xFFFF0000u);
}
__device__ __forceinline__ float bf2f(unsigned short v) {
    return __uint_as_float(((unsigned)v) << 16);
}
// packed bf16 pair add: (a.lo+b.lo, a.hi+b.hi) with RNE re-round
__device__ __forceinline__ unsigned addpk(unsigned a, unsigned b) {
    float lo = __uint_as_float(a << 16) + __uint_as_float(b << 16);
    float hi = __uint_as_float(a & 0xFFFF0000u) + __uint_as_float(b & 0xFFFF0000u);
    return (unsigned)f2bf(lo) | ((unsigned)f2bf(hi) << 16);
}

// ---------------- node encoder: h = x @ W_node + b_node (f32 + bf16 copies) ----------------
__global__ __launch_bounds__(256) void k_node_encode(
    const float* __restrict__ x, const float* __restrict__ Wn,
    const float* __restrict__ bn, float* __restrict__ h, unsigned short* __restrict__ hb) {
    int n = blockIdx.x * 4 + (threadIdx.x >> 6);
    int c = threadIdx.x & 63;
    if (n >= N_NODES) return;
    float acc = bn[c];
    const float* xr = x + n * 16;
    #pragma unroll
    for (int k = 0; k < 16; ++k) acc = fmaf(xr[k], Wn[k * 64 + c], acc);
    h[n * 64 + c] = acc;
    hb[n * 64 + c] = f2bf(acc);
}

// ---------------- edge CSR build: histogram + per-edge rank ----------------
__global__ __launch_bounds__(256) void k_hist_rank(const int* __restrict__ ei,
                                                   int* __restrict__ cnt, int* __restrict__ rank) {
    int i = blockIdx.x * blockDim.x + threadIdx.x;
    if (i >= N_EDGES) return;
    rank[i] = atomicAdd(&cnt[ei[N_EDGES + i]], 1);
}

__global__ __launch_bounds__(256) void k_scan1(const int* __restrict__ cnt,
                                               int* __restrict__ inc, int* __restrict__ bsum) {
    __shared__ int sh[256];
    int gi = blockIdx.x * 256 + threadIdx.x;
    int v = (gi < N_NODES + 1) ? cnt[gi] : 0;
    sh[threadIdx.x] = v;
    __syncthreads();
    #pragma unroll
    for (int d = 1; d < 256; d <<= 1) {
        int t = (threadIdx.x >= d) ? sh[threadIdx.x - d] : 0;
        __syncthreads();
        sh[threadIdx.x] += t;
        __syncthreads();
    }
    if (gi < N_NODES + 1) inc[gi] = sh[threadIdx.x];
    if (threadIdx.x == 255) bsum[blockIdx.x] = sh[255];
}

__global__ __launch_bounds__(256) void k_scan2(int* __restrict__ bsum) {
    __shared__ int sh[256];
    int t = threadIdx.x;
    sh[t] = (t < SCAN_NB) ? bsum[t] : 0;
    __syncthreads();
    #pragma unroll
    for (int d = 1; d < 256; d <<= 1) {
        int v = (t >= d) ? sh[t - d] : 0;
        __syncthreads();
        sh[t] += v;
        __syncthreads();
    }
    if (t < SCAN_NB) bsum[t] = (t == 0) ? 0 : sh[t - 1];
}

__global__ __launch_bounds__(256) void k_scan3(const int* __restrict__ inc,
                                               const int* __restrict__ cnt,
                                               const int* __restrict__ bsum,
                                               int* __restrict__ offs) {
    int gi = blockIdx.x * 256 + threadIdx.x;
    if (gi < N_NODES + 1) offs[gi] = bsum[blockIdx.x] + inc[gi] - cnt[gi];
}

// pure random 4B store, no atomics: p = offs[d] + rank[i]
__global__ __launch_bounds__(256) void k_scatter(
    const int* __restrict__ ei, const float* __restrict__ eattr,
    const int* __restrict__ offs, const int* __restrict__ rank,
    unsigned int* __restrict__ s_pack) {
    int i = blockIdx.x * blockDim.x + threadIdx.x;
    if (i >= N_EDGES) return;
    int d = ei[N_EDGES + i];
    int p = offs[d] + rank[i];
    unsigned pk = ((unsigned)f2bf(eattr[i]) << 16) | (unsigned)(ei[i] & 0xFFFF);
    s_pack[p] = pk;
}

// ---------------- zb = bf16(relu(LN(h, g, b))) ----------------
__global__ __launch_bounds__(256) void k_ln_relu(
    const float* __restrict__ h, const float* __restrict__ g,
    const float* __restrict__ b, unsigned short* __restrict__ zb) {
    int wid = (blockIdx.x * blockDim.x + threadIdx.x) >> 6;
    int lane = threadIdx.x & 63;
    if (wid >= N_NODES) return;
    float v = h[wid * 64 + lane];
    float sx = v, sq = v * v;
    #pragma unroll
    for (int o = 32; o > 0; o >>= 1) {
        sx += __shfl_xor(sx, o, 64);
        sq += __shfl_xor(sq, o, 64);
    }
    float mu = sx * (1.f / 64.f);
    float var = sq * (1.f / 64.f) - mu * mu;
    float zz = fmaxf((v - mu) * rsqrtf(var + 1e-5f) * g[lane] + b[lane], 0.f);
    zb[wid * 64 + lane] = f2bf(zz);
}

// ---------------- softmax aggregation (shift-free: logits << 88), one wave/node ----------------
__global__ __launch_bounds__(256) void k_agg(
    const unsigned short* __restrict__ zb, const int* __restrict__ offs,
    const unsigned int* __restrict__ s_pack,
    const float* __restrict__ We, const float* __restrict__ be,
    const float* __restrict__ t, int layer, unsigned short* __restrict__ aggb) {
    int wid = (blockIdx.x * blockDim.x + threadIdx.x) >> 6;
    int lane = threadIdx.x & 63;
    if (wid >= N_NODES) return;
    int beg = offs[wid], end = offs[wid + 1];
    float we = We[lane], bev = be[lane];
    float tl = t[layer];
    float s = 0.f, num = 0.f;
    int i = beg;
    for (; i + 3 < end; i += 4) {
        unsigned pk0 = s_pack[i], pk1 = s_pack[i + 1], pk2 = s_pack[i + 2], pk3 = s_pack[i + 3];
        float z0 = bf2f(zb[(pk0 & 0xFFFFu) * 64 + lane]);
        float z1 = bf2f(zb[(pk1 & 0xFFFFu) * 64 + lane]);
        float z2 = bf2f(zb[(pk2 & 0xFFFFu) * 64 + lane]);
        float z3 = bf2f(zb[(pk3 & 0xFFFFu) * 64 + lane]);
        float msg0 = fmaxf(z0 + fmaf(bfbits_hi(pk0), we, bev), 0.f) + 1e-7f;
        float msg1 = fmaxf(z1 + fmaf(bfbits_hi(pk1), we, bev), 0.f) + 1e-7f;
        float msg2 = fmaxf(z2 + fmaf(bfbits_hi(pk2), we, bev), 0.f) + 1e-7f;
        float msg3 = fmaxf(z3 + fmaf(bfbits_hi(pk3), we, bev), 0.f) + 1e-7f;
        float p0 = __expf(msg0 * tl), p1 = __expf(msg1 * tl);
        float p2 = __expf(msg2 * tl), p3 = __expf(msg3 * tl);
        s += (p0 + p1) + (p2 + p3);
        num += fmaf(p0, msg0, p1 * msg1) + fmaf(p2, msg2, p3 * msg3);
    }
    for (; i < end; ++i) {
        unsigned pk = s_pack[i];
        float zz = bf2f(zb[(pk & 0xFFFFu) * 64 + lane]);
        float msg = fmaxf(zz + fmaf(bfbits_hi(pk), we, bev), 0.f) + 1e-7f;
        float p = __expf(msg * tl);
        s += p;
        num = fmaf(p, msg, num);
    }
    aggb[wid * 64 + lane] = f2bf(num / (s + 1e-16f));
}

// ---------------- fused MLP via MFMA bf16 (one wave per 16 nodes) ----------------
__global__ __launch_bounds__(256) void k_mlp(
    const unsigned short* __restrict__ aggb, const unsigned short* __restrict__ zb,
    float* __restrict__ h, const float* __restrict__ W1, const float* __restrict__ b1,
    const float* __restrict__ g1, const float* __restrict__ be1,
    const float* __restrict__ W2, const float* __restrict__ b2, int addres) {
    __shared__ unsigned short vbuf[4][16 * 64];
    __shared__ unsigned short ubuf[4][16 * 128];
    int lane = threadIdx.x & 63;
    int wave = threadIdx.x >> 6;
    int col = lane & 15, quad = lane >> 4;
    unsigned short* vb = vbuf[wave];
    unsigned short* ub = ubuf[wave];

    short8 w1f[2][8];
    #pragma unroll
    for (int s = 0; s < 2; ++s)
        #pragma unroll
        for (int t = 0; t < 8; ++t)
            #pragma unroll
            for (int j = 0; j < 8; ++j)
                w1f[s][t][j] = (short)f2bf(W1[(s * 32 + quad * 8 + j) * 128 + t * 16 + col]);
    short8 w2f[4][4];
    #pragma unroll
    for (int s = 0; s < 4; ++s)
        #pragma unroll
        for (int t = 0; t < 4; ++t)
            #pragma unroll
            for (int j = 0; j < 8; ++j)
                w2f[s][t][j] = (short)f2bf(W2[(s * 32 + quad * 8 + j) * 64 + t * 16 + col]);

    float b1f[8], g1f[8], e1f[8];
    #pragma unroll
    for (int t = 0; t < 8; ++t) {
        int ch = t * 16 + col;
        b1f[t] = b1[ch]; g1f[t] = g1[ch]; e1f[t] = be1[ch];
    }
    float b2f_[4];
    #pragma unroll
    for (int t = 0; t < 4; ++t) b2f_[t] = b2[t * 16 + col];

    int nd = lane >> 2;
    int cg = (lane & 3) * 16;

    for (int g = blockIdx.x * 4 + wave; g < N_NODES / 16; g += gridDim.x * 4) {
        int n0 = g * 16;
        // stage v = bf16(aggb + zb) into LDS [16][64]  (2 uint4 loads per array per lane)
        const uint4* ap = (const uint4*)(aggb + (size_t)(n0 + nd) * 64 + cg);
        const uint4* zp = (const uint4*)(zb + (size_t)(n0 + nd) * 64 + cg);
        uint4 a0 = ap[0], a1 = ap[1], z0 = zp[0], z1 = zp[1];
        uint4 r0, r1;
        r0.x = addpk(a0.x, z0.x); r0.y = addpk(a0.y, z0.y);
        r0.z = addpk(a0.z, z0.z); r0.w = addpk(a0.w, z0.w);
        r1.x = addpk(a1.x, z1.x); r1.y = addpk(a1.y, z1.y);
        r1.z = addpk(a1.z, z1.z); r1.w = addpk(a1.w, z1.w);
        uint4* vdst = (uint4*)&vb[nd * 64 + cg];
        vdst[0] = r0;
        vdst[1] = r1;

        short8 af0 = *(const short8*)&vb[col * 64 + quad * 8];
        short8 af1 = *(const short8*)&vb[col * 64 + 32 + quad * 8];
        f32x4 au[8];
        #pragma unroll
        for (int t = 0; t < 8; ++t) {
            f32x4 c = {0.f, 0.f, 0.f, 0.f};
            c = __builtin_amdgcn_mfma_f32_16x16x32_bf16(af0, w1f[0][t], c, 0, 0, 0);
            c = __builtin_amdgcn_mfma_f32_16x16x32_bf16(af1, w1f[1][t], c, 0, 0, 0);
            au[t] = c;
        }
        #pragma unroll
        for (int r = 0; r < 4; ++r) {
            float sx = 0.f, sq = 0.f;
            #pragma unroll
            for (int t = 0; t < 8; ++t) {
                float v = au[t][r] + b1f[t];
                sx += v; sq += v * v;
            }
            #pragma unroll
            for (int mask = 1; mask < 16; mask <<= 1) {
                sx += __shfl_xor(sx, mask, 64);
                sq += __shfl_xor(sq, mask, 64);
            }
            float mu = sx * (1.f / 128.f);
            float var = sq * (1.f / 128.f) - mu * mu;
            float rs = rsqrtf(var + 1e-5f);
            int row = quad * 4 + r;
            #pragma unroll
            for (int t = 0; t < 8; ++t) {
                float v = au[t][r] + b1f[t];
                float y = fmaxf(fmaf((v - mu) * rs, g1f[t], e1f[t]), 0.f);
                ub[row * 128 + t * 16 + col] = f2bf(y);
            }
        }
        f32x4 oc[4];
        #pragma unroll
        for (int t = 0; t < 4; ++t) oc[t] = (f32x4){0.f, 0.f, 0.f, 0.f};
        #pragma unroll
        for (int s = 0; s < 4; ++s) {
            short8 a = *(const short8*)&ub[col * 128 + s * 32 + quad * 8];
            #pragma unroll
            for (int t = 0; t < 4; ++t)
                oc[t] = __builtin_amdgcn_mfma_f32_16x16x32_bf16(a, w2f[s][t], oc[t], 0, 0, 0);
        }
        #pragma unroll
        for (int t = 0; t < 4; ++t) {
            #pragma unroll
            for (int r = 0; r < 4; ++r) {
                int n = n0 + quad * 4 + r;
                int ch = t * 16 + col;
                float val = oc[t][r] + b2f_[t];
                float* hp = &h[(size_t)n * 64 + ch];
                if (addres) val += *hp;
                *hp = val;
            }
        }
    }
}

// ---------------- final LN/relu + pool partials (2-node ILP, fused sum/sumsq) ----------------
__global__ __launch_bounds__(256) void k_pool(
    const float* __restrict__ h, const float* __restrict__ g, const float* __restrict__ b,
    float* __restrict__ pb_sum, float* __restrict__ pb_max) {
    __shared__ float ssum[4][64];
    __shared__ float smax[4][64];
    int lane = threadIdx.x & 63;
    int wave = threadIdx.x >> 6;
    int gw = blockIdx.x * 4 + wave;
    int nw = gridDim.x * 4;
    float ga = g[lane], ba = b[lane];
    float lsum = 0.f, lmax = 0.f;
    int n = gw;
    for (; n + nw < N_NODES; n += 2 * nw) {
        int n2 = n + nw;
        float v0 = h[(size_t)n * 64 + lane];
        float v1 = h[(size_t)n2 * 64 + lane];
        float sx0 = v0, sq0 = v0 * v0, sx1 = v1, sq1 = v1 * v1;
        #pragma unroll
        for (int o = 32; o > 0; o >>= 1) {
            sx0 += __shfl_xor(sx0, o, 64);
            sq0 += __shfl_xor(sq0, o, 64);
            sx1 += __shfl_xor(sx1, o, 64);
            sq1 += __shfl_xor(sq1, o, 64);
        }
        float mu0 = sx0 * (1.f / 64.f), mu1 = sx1 * (1.f / 64.f);
        float var0 = sq0 * (1.f / 64.f) - mu0 * mu0;
        float var1 = sq1 * (1.f / 64.f) - mu1 * mu1;
        float z0 = fmaxf((v0 - mu0) * rsqrtf(var0 + 1e-5f) * ga + ba, 0.f);
        float z1 = fmaxf((v1 - mu1) * rsqrtf(var1 + 1e-5f) * ga + ba, 0.f);
        lsum += z0 + z1;
        lmax = fmaxf(lmax, fmaxf(z0, z1));
    }
    if (n < N_NODES) {
        float v = h[(size_t)n * 64 + lane];
        float sx = v, sq = v * v;
        #pragma unroll
        for (int o = 32; o > 0; o >>= 1) {
            sx += __shfl_xor(sx, o, 64);
            sq += __shfl_xor(sq, o, 64);
        }
        float mu = sx * (1.f / 64.f);
        float var = sq * (1.f / 64.f) - mu * mu;
        float zz = fmaxf((v - mu) * rsqrtf(var + 1e-5f) * ga + ba, 0.f);
        lsum += zz;
        lmax = fmaxf(lmax, zz);
    }
    ssum[wave][lane] = lsum;
    smax[wave][lane] = lmax;
    __syncthreads();
    if (wave == 0) {
        float s = ssum[0][lane] + ssum[1][lane] + ssum[2][lane] + ssum[3][lane];
        float mx = fmaxf(fmaxf(smax[0][lane], smax[1][lane]),
                         fmaxf(smax[2][lane], smax[3][lane]));
        pb_sum[blockIdx.x * 64 + lane] = s;
        pb_max[blockIdx.x * 64 + lane] = mx;
    }
}

// ---------------- head: reduce block partials -> bins -> emb @ W_lin + b_lin ----------------
__global__ __launch_bounds__(256) void k_head(
    const float* __restrict__ pb_sum, const float* __restrict__ pb_max,
    const float* __restrict__ Wl, const float* __restrict__ bl, float* __restrict__ out) {
    __shared__ float sa4[4][64], sm4[4][64];
    __shared__ float sa[64], sm[64], emb[64];
    int t = threadIdx.x;
    int ch = t & 63, part = t >> 6;          // 4 partial-slices per channel
    float s = 0.f, mx = 0.f;
    for (int b = part; b < NBP; b += 4) {
        s += pb_sum[b * 64 + ch];
        mx = fmaxf(mx, pb_max[b * 64 + ch]);
    }
    sa4[part][ch] = s; sm4[part][ch] = mx;
    __syncthreads();
    if (t < 64) {
        sa[t] = sa4[0][t] + sa4[1][t] + sa4[2][t] + sa4[3][t];
        sm[t] = fmaxf(fmaxf(sm4[0][t], sm4[1][t]), fmaxf(sm4[2][t], sm4[3][t]));
    }
    __syncthreads();
    if (t < 64) {
        if (t < 32) {
            emb[t] = (sa[2 * t] + sa[2 * t + 1]) * (0.5f / (float)N_NODES);
        } else {
            int i = t - 32;
            emb[t] = fmaxf(sm[2 * i], sm[2 * i + 1]);
        }
    }
    __syncthreads();
    if (t < 64) {
        float acc = bl[t];
        for (int k = 0; k < 64; ++k) acc = fmaf(emb[k], Wl[k * 64 + t], acc);
        out[t] = acc;
    }
}

extern "C" void kernel_launch(void* const* d_in, const int* in_sizes, int n_in,
                              void* d_out, int out_size, void* d_ws, size_t ws_size,
                              hipStream_t stream) {
    const float* x     = (const float*)d_in[0];
    const float* eattr = (const float*)d_in[1];
    const int*   ei    = (const int*)d_in[2];
    const float* Wn    = (const float*)d_in[3];
    const float* bn    = (const float*)d_in[4];
    const float* We    = (const float*)d_in[5];
    const float* be    = (const float*)d_in[6];
    const float* t     = (const float*)d_in[7];
    const float* W1    = (const float*)d_in[8];
    const float* b1    = (const float*)d_in[9];
    const float* lg    = (const float*)d_in[10];
    const float* lb    = (const float*)d_in[11];
    const float* W2    = (const float*)d_in[12];
    const float* b2    = (const float*)d_in[13];
    const float* ng    = (const float*)d_in[14];
    const float* nb    = (const float*)d_in[15];
    const float* Wl    = (const float*)d_in[16];
    const float* bl    = (const float*)d_in[17];
    float* out = (float*)d_out;

    char* p = (char*)d_ws;
    float* h   = (float*)p; p += (size_t)N_NODES * 64 * 4;
    unsigned short* zb   = (unsigned short*)p; p += (size_t)N_NODES * 64 * 2;
    unsigned short* aggb = (unsigned short*)p; p += (size_t)N_NODES * 64 * 2;
    unsigned int* s_pack = (unsigned int*)p; p += (size_t)N_EDGES * 4;
    int* cnt    = (int*)p;  p += (size_t)(N_NODES + 4) * 4;
    int* offs   = (int*)p;  p += (size_t)(N_NODES + 4) * 4;
    int* inc    = (int*)p;  p += (size_t)(N_NODES + 4) * 4;
    int* bsum   = (int*)p;  p += (size_t)256 * 4;
    float* pb_sum = (float*)p; p += (size_t)NBP * 64 * 4;
    float* pb_max = (float*)p; p += (size_t)NBP * 64 * 4;
    int* rank = (int*)p;    p += (size_t)N_EDGES * 4;

    hipMemsetAsync(cnt, 0, (N_NODES + 1) * sizeof(int), stream);

    k_node_encode<<<(N_NODES + 3) / 4, 256, 0, stream>>>(x, Wn, bn, h, zb);
    k_hist_rank<<<(N_EDGES + 255) / 256, 256, 0, stream>>>(ei, cnt, rank);
    k_scan1<<<SCAN_NB, 256, 0, stream>>>(cnt, inc, bsum);
    k_scan2<<<1, 256, 0, stream>>>(bsum);
    k_scan3<<<SCAN_NB, 256, 0, stream>>>(inc, cnt, bsum, offs);
    k_scatter<<<(N_EDGES + 255) / 256, 256, 0, stream>>>(ei, eattr, offs, rank, s_pack);

    for (int i = 0; i < 3; ++i) {
        if (i > 0) {
            k_ln_relu<<<(N_NODES + 3) / 4, 256, 0, stream>>>(h, ng + i * 64, nb + i * 64, zb);
        }
        k_agg<<<(N_NODES + 3) / 4, 256, 0, stream>>>(zb, offs, s_pack, We, be, t, i, aggb);
        k_mlp<<<782, 256, 0, stream>>>(
            aggb, zb, h, W1 + (size_t)i * 64 * 128, b1 + i * 128, lg + i * 128, lb + i * 128,
            W2 + (size_t)i * 128 * 64, b2 + i * 64, i > 0);
    }

    k_pool<<<NBP, 256, 0, stream>>>(h, ng, nb, pb_sum, pb_max);
    k_head<<<1, 256, 0, stream>>>(pb_sum, pb_max, Wl, bl, out);
}